// Round 16
// baseline (524.907 us; speedup 1.0000x reference)
//
#include <hip/hip_runtime.h>
#include <hip/hip_bf16.h>

using short8 = __attribute__((ext_vector_type(8))) short;
using f32x16 = __attribute__((ext_vector_type(16))) float;
using us4    = __attribute__((ext_vector_type(4))) unsigned short;

#define NHID 15872

__device__ __forceinline__ unsigned short f2bf(float f) {
  unsigned u = __builtin_bit_cast(unsigned, f);
  u += 0x7fff + ((u >> 16) & 1);          // RNE
  return (unsigned short)(u >> 16);
}
__device__ __forceinline__ short f2bf_hw(float f) {
  __hip_bfloat16 h = __float2bfloat16(f);
  return __builtin_bit_cast(short, h);
}
__device__ __forceinline__ float bf2f(unsigned short h) {
  return __builtin_bit_cast(float, ((unsigned)h) << 16);
}

// async global->LDS, 16B/lane. LDS dest = wave-uniform base + lane*16.
__device__ __forceinline__ void gload16(const void* g, void* l) {
  __builtin_amdgcn_global_load_lds(
      (const __attribute__((address_space(1))) unsigned int*)g,
      (__attribute__((address_space(3))) unsigned int*)l, 16, 0, 0);
}

// packed-A layout: (row,k) -> (k>>4)*4096 + (row + 256*((k>>3)&1))*8 + (k&7)
__device__ __forceinline__ size_t pk_idx(int row, int col) {
  return (size_t)(col >> 4) * 4096 +
         (size_t)(row + 256 * ((col >> 3) & 1)) * 8 + (col & 7);
}

// ---------------- kernel 0: x fp32 -> packed bf16 ----------------
__global__ void cvt_x_pack(const float* __restrict__ x, unsigned short* __restrict__ xpk) {
  int g = blockIdx.x * 256 + threadIdx.x;       // 16384 chunks of 8
  int row = g >> 6, k0 = (g & 63) * 8;
  const float* p = x + (size_t)row * 512 + k0;
  float4 a = *reinterpret_cast<const float4*>(p);
  float4 b = *reinterpret_cast<const float4*>(p + 4);
  us4 o0, o1;
  o0[0] = f2bf(a.x); o0[1] = f2bf(a.y); o0[2] = f2bf(a.z); o0[3] = f2bf(a.w);
  o1[0] = f2bf(b.x); o1[1] = f2bf(b.y); o1[2] = f2bf(b.z); o1[3] = f2bf(b.w);
  unsigned short* d = xpk + pk_idx(row, k0);
  *reinterpret_cast<us4*>(d)     = o0;
  *reinterpret_cast<us4*>(d + 4) = o1;
}

// ---------------- main GEMM v16: 2KB-chunk B staging ----------------
// BM=64, BN=512, BK=16. 512 thr = 8 waves; wave w = all 64 rows x cols
// w*64..+63; acc = 4 x f32x16. Ring-2 LDS (64 KB) -> 2 WG/CU. Each staged
// B-row = 2 KB CONTIGUOUS (2 back-to-back 1KB gload16) — DRAM page test.
// 4-way m-split shares B; SWZ decode co-locates the 4 m-variants of each
// (n,ks) on one XCD (block ids = same mod 8) -> 3 of 4 reads are L2 hits.
// OUTMODE: 0 = bias+relu -> packed bf16, 1 = bf16 partials, 2 = rowmajor.

#define WAITV(N) asm volatile("s_waitcnt vmcnt(" #N ")" ::: "memory")

// wave w stages rows t*16 + 2w, 2w+1; each row = 2 x 1KB instrs, contiguous
#define STAGEB(BUF, T) do { \
    const float* bp_ = bsrc + (size_t)((T) * 16 + 2 * w) * NHID; \
    gload16(bp_,              &Blds[BUF][(2 * w) * 512]); \
    gload16(bp_ + 256,        &Blds[BUF][(2 * w) * 512 + 256]); \
    gload16(bp_ + NHID,       &Blds[BUF][(2 * w + 1) * 512]); \
    gload16(bp_ + NHID + 256, &Blds[BUF][(2 * w + 1) * 512 + 256]); \
  } while (0)

#define LOADA(T) do { \
    const unsigned short* ap_ = asrc + (size_t)(T) * 4096; \
    rA[0] = *reinterpret_cast<const short8*>(ap_); \
    rA[1] = *reinterpret_cast<const short8*>(ap_ + 256); \
  } while (0)

#define COMPUTE(BUF) do { \
    const float* bb_ = &Blds[BUF][0]; \
    _Pragma("unroll") \
    for (int nb_ = 0; nb_ < 2; ++nb_) { \
      float tf_[8]; \
      _Pragma("unroll") \
      for (int jj_ = 0; jj_ < 8; ++jj_) \
        tf_[jj_] = bb_[(hi * 8 + jj_) * 512 + w * 64 + nb_ * 32 + l31]; \
      short8 bfr_; \
      _Pragma("unroll") \
      for (int jj_ = 0; jj_ < 8; ++jj_) bfr_[jj_] = f2bf_hw(tf_[jj_]); \
      acc[nb_]     = __builtin_amdgcn_mfma_f32_32x32x16_bf16(rA[0], bfr_, acc[nb_],     0, 0, 0); \
      acc[2 + nb_] = __builtin_amdgcn_mfma_f32_32x32x16_bf16(rA[1], bfr_, acc[2 + nb_], 0, 0, 0); \
    } \
  } while (0)

template<int OUTMODE, bool SWZ>
__global__ __launch_bounds__(512, 4)
void gemm_v16(const unsigned short* __restrict__ Apk, int KC,
              const float* __restrict__ B, const float* __restrict__ bias,
              unsigned short* __restrict__ Cf, unsigned short* __restrict__ Cpb)
{
  __shared__ float Blds[2][16 * 512];   // 64 KB ring-2

  int m0, nidx, ks0;
  if (SWZ) {
    int b = blockIdx.x;                  // 512 slots; 496 active
    int low3 = b & 7, m = (b >> 3) & 3, high = b >> 5;
    int nk = high * 8 + low3;
    if (nk >= 124) return;
    ks0 = nk & 3; nidx = nk >> 2; m0 = m * 64;
  } else {
    m0 = blockIdx.x * 64; nidx = blockIdx.y; ks0 = blockIdx.z;
  }
  const int n0   = nidx * 512;
  const int k0   = ks0 * KC;
  const int tid  = threadIdx.x;
  const int w    = tid >> 6;
  const int lane = tid & 63;
  const int l31  = lane & 31;
  const int hi   = lane >> 5;

  f32x16 acc[4] = {};   // [rb*2 + nb]
  short8 rA[2];

  // B stage src: per-lane cols n0 + lane*4 (1 KB per wave-instr)
  const float* bsrc = B + (size_t)k0 * NHID + n0 + lane * 4;
  // A frag src (packed): rows m0 + rb*32 + l31, k = t*16 + hi*8 + e
  const unsigned short* asrc = Apk + (size_t)(k0 >> 4) * 4096 +
                               (size_t)(m0 + l31 + 256 * hi) * 8;

  const int NT = KC >> 4;

  STAGEB(0, 0);
  for (int t = 0; t < NT; ++t) {
    WAITV(0);                                // drain stage(t) (issued last iter)
    __builtin_amdgcn_sched_barrier(0);
    __builtin_amdgcn_s_barrier();            // all waves' stage(t) in LDS
    LOADA(t);                                 // A first in FIFO
    if (t + 1 < NT) STAGEB((t + 1) & 1, t + 1);   // stays in flight thru compute
    COMPUTE(t & 1);                           // A-wait = vmcnt(4), leaves stage
  }

  // epilogue: verified mapping col=base+l31, row=(reg&3)+8*(reg>>2)+4*hi
#pragma unroll
  for (int rb = 0; rb < 2; ++rb) {
#pragma unroll
    for (int nb = 0; nb < 2; ++nb) {
      int col = n0 + w * 64 + nb * 32 + l31;
      float bv = (OUTMODE != 1) ? bias[col] : 0.f;
#pragma unroll
      for (int reg = 0; reg < 16; ++reg) {
        int row = m0 + rb * 32 + (reg & 3) + 8 * (reg >> 2) + 4 * hi;
        float v = acc[rb * 2 + nb][reg];
        if (OUTMODE == 0) {
          v += bv; v = v > 0.f ? v : 0.f;
          Cf[pk_idx(row, col)] = f2bf(v);
        } else if (OUTMODE == 1) {
          Cpb[(size_t)ks0 * 256 * NHID + (size_t)row * NHID + col] = f2bf(v);
        } else {
          v += bv; v = v > 0.f ? v : 0.f;
          Cf[(size_t)row * NHID + col] = f2bf(v);
        }
      }
    }
  }
}

// ---------------- reduce bf16 partials: out = relu(sum + bias) -> bf16 ----------------
template<bool PACK>
__global__ void reduce_hb(const unsigned short* __restrict__ part,
                          const float* __restrict__ bias,
                          unsigned short* __restrict__ out, int S) {
  int g8 = blockIdx.x * 256 + threadIdx.x;     // < 256*1984 (chunks of 8)
  int row = g8 / 1984;
  int c   = (g8 - row * 1984) * 8;
  size_t off = (size_t)row * NHID + c;
  float s[8] = {0.f, 0.f, 0.f, 0.f, 0.f, 0.f, 0.f, 0.f};
  for (int k = 0; k < S; ++k) {
    short8 p = *reinterpret_cast<const short8*>(part + (size_t)k * 256 * NHID + off);
#pragma unroll
    for (int j = 0; j < 8; ++j) s[j] += bf2f((unsigned short)p[j]);
  }
  short8 o;
#pragma unroll
  for (int j = 0; j < 8; ++j) {
    float v = s[j] + bias[c + j];
    v = v > 0.f ? v : 0.f;
    o[j] = (short)f2bf(v);
  }
  if (PACK) *reinterpret_cast<short8*>(out + pk_idx(row, c)) = o;
  else      *reinterpret_cast<short8*>(out + off) = o;
}

// ---------------- fold Wout [15872][992] -> Wv [15872][32] ----------------
__global__ void wv_fold(const float* __restrict__ Wout, float* __restrict__ Wv) {
  int g = blockIdx.x * 256 + threadIdx.x;
  int k = g >> 5, c = g & 31;
  const float* row = Wout + (size_t)k * 992;
  float s = 0.f;
#pragma unroll
  for (int o = 0; o < 32; ++o) {
    if (o == c) continue;
    int i = c < o ? c : o;
    int j = c < o ? o : c;
    int p = 31 * i - (i * (i - 1)) / 2 + (j - i - 1);
    s += row[2 * p + (c > o ? 1 : 0)];
  }
  Wv[g] = s;
}

// ---------------- votes partial = h2 @ Wv, K-split 32 ----------------
__global__ void votes_partial(const unsigned short* __restrict__ h2,
                              const float* __restrict__ Wv,
                              float* __restrict__ part) {
  int bm = blockIdx.x >> 5;
  int ks = blockIdx.x & 31;
  int r  = bm * 8 + (threadIdx.x >> 5);
  int c  = threadIdx.x & 31;
  const unsigned short* hrow = h2 + (size_t)r * NHID + ks * 496;
  const float* wp = Wv + (size_t)(ks * 496) * 32 + c;
  float s = 0.f;
  for (int k0 = 0; k0 < 496; k0 += 8) {
    short8 hv = *reinterpret_cast<const short8*>(hrow + k0);
#pragma unroll
    for (int j = 0; j < 8; ++j)
      s += bf2f((unsigned short)hv[j]) * wp[(size_t)(k0 + j) * 32];
  }
  part[(size_t)(ks * 256 + r) * 32 + c] = s;
}

// ---------------- reduce votes + bias-fold ----------------
__global__ void votes_reduce(const float* __restrict__ part,
                             const float* __restrict__ bout,
                             float* __restrict__ out) {
  int g = blockIdx.x * 256 + threadIdx.x;
  int c = g & 31;
  float s = 0.f;
#pragma unroll
  for (int ks = 0; ks < 32; ++ks) s += part[(size_t)ks * 8192 + g];
  float bv = 0.f;
#pragma unroll
  for (int o = 0; o < 32; ++o) {
    if (o == c) continue;
    int i = c < o ? c : o;
    int j = c < o ? o : c;
    int p = 31 * i - (i * (i - 1)) / 2 + (j - i - 1);
    bv += bout[2 * p + (c > o ? 1 : 0)];
  }
  out[g] = s + bv;
}

extern "C" void kernel_launch(void* const* d_in, const int* in_sizes, int n_in,
                              void* d_out, int out_size, void* d_ws, size_t ws_size,
                              hipStream_t stream) {
  const float* x    = (const float*)d_in[0];
  const float* W1   = (const float*)d_in[1];
  const float* b1   = (const float*)d_in[2];
  const float* W2   = (const float*)d_in[3];
  const float* b2   = (const float*)d_in[4];
  const float* Wout = (const float*)d_in[5];
  const float* bout = (const float*)d_in[6];
  float* out = (float*)d_out;

  char* ws = (char*)d_ws;
  unsigned short* xpk  = (unsigned short*)(ws);                     // 262144
  unsigned short* h1pk = (unsigned short*)(ws + 262144);            // 8126464
  unsigned short* h2   = (unsigned short*)(ws + 8388608);           // 8126464
  float*          Wv   = (float*)(ws + 16515072);                   // 2031616
  float*          part = (float*)(ws + 18546688);                   // 1048576
  unsigned short* pb   = (unsigned short*)(ws + 19595264);          // 4*256*NHID*2 = 32.5 MB

  const size_t PARTB = (size_t)256 * NHID * 2;   // 8,126,464 per bf16 partial
  const bool split = ws_size >= 19595264ull + 4 * PARTB;

  hipLaunchKernelGGL(cvt_x_pack, dim3(64), dim3(256), 0, stream, x, xpk);
  if (split) {
    // GEMM1: K=512 unsplit -> packed h1 directly (bias+relu)
    hipLaunchKernelGGL((gemm_v16<0, false>), dim3(4, 31, 1), dim3(512), 0, stream,
                       xpk, 512, W1, b1, h1pk, (unsigned short*)nullptr);
    // GEMM2: K=15872 split 4 ways; 2KB-chunk B, m-variants co-located per XCD
    hipLaunchKernelGGL((gemm_v16<1, true>), dim3(512), dim3(512), 0, stream,
                       h1pk, 3968, W2, (const float*)nullptr,
                       (unsigned short*)nullptr, pb);
    hipLaunchKernelGGL((reduce_hb<false>), dim3(1984), dim3(256), 0, stream,
                       pb, b2, h2, 4);
  } else {
    hipLaunchKernelGGL((gemm_v16<0, false>), dim3(4, 31, 1), dim3(512), 0, stream,
                       xpk, 512, W1, b1, h1pk, (unsigned short*)nullptr);
    hipLaunchKernelGGL((gemm_v16<2, false>), dim3(4, 31, 1), dim3(512), 0, stream,
                       h1pk, NHID, W2, b2, h2, (unsigned short*)nullptr);
  }
  hipLaunchKernelGGL(wv_fold,       dim3(1984), dim3(256), 0, stream, Wout, Wv);
  hipLaunchKernelGGL(votes_partial, dim3(1024), dim3(256), 0, stream, h2, Wv, part);
  hipLaunchKernelGGL(votes_reduce,  dim3(32),   dim3(256), 0, stream, part, bout, out);
}

// Round 17
// 394.492 us; speedup vs baseline: 1.3306x; 1.3306x over previous
//
#include <hip/hip_runtime.h>
#include <hip/hip_bf16.h>

using short8 = __attribute__((ext_vector_type(8))) short;
using f32x16 = __attribute__((ext_vector_type(16))) float;
using us4    = __attribute__((ext_vector_type(4))) unsigned short;

#define NHID 15872
#define PLANE ((size_t)256 * NHID)

__device__ __forceinline__ unsigned short f2bf(float f) {
  unsigned u = __builtin_bit_cast(unsigned, f);
  u += 0x7fff + ((u >> 16) & 1);          // RNE
  return (unsigned short)(u >> 16);
}
__device__ __forceinline__ short f2bf_hw(float f) {
  __hip_bfloat16 h = __float2bfloat16(f);
  return __builtin_bit_cast(short, h);
}
__device__ __forceinline__ float bf2f(unsigned short h) {
  return __builtin_bit_cast(float, ((unsigned)h) << 16);
}

// async global->LDS, 16B/lane. LDS dest = wave-uniform base + lane*16.
__device__ __forceinline__ void gload16(const void* g, void* l) {
  __builtin_amdgcn_global_load_lds(
      (const __attribute__((address_space(1))) unsigned int*)g,
      (__attribute__((address_space(3))) unsigned int*)l, 16, 0, 0);
}

// packed-A layout: (row,k) -> (k>>4)*4096 + (row + 256*((k>>3)&1))*8 + (k&7)
__device__ __forceinline__ size_t pk_idx(int row, int col) {
  return (size_t)(col >> 4) * 4096 +
         (size_t)(row + 256 * ((col >> 3) & 1)) * 8 + (col & 7);
}

// ---------------- kernel 0: x fp32 -> packed bf16 ----------------
__global__ void cvt_x_pack(const float* __restrict__ x, unsigned short* __restrict__ xpk) {
  int g = blockIdx.x * 256 + threadIdx.x;       // 16384 chunks of 8
  int row = g >> 6, k0 = (g & 63) * 8;
  const float* p = x + (size_t)row * 512 + k0;
  float4 a = *reinterpret_cast<const float4*>(p);
  float4 b = *reinterpret_cast<const float4*>(p + 4);
  us4 o0, o1;
  o0[0] = f2bf(a.x); o0[1] = f2bf(a.y); o0[2] = f2bf(a.z); o0[3] = f2bf(a.w);
  o1[0] = f2bf(b.x); o1[1] = f2bf(b.y); o1[2] = f2bf(b.z); o1[3] = f2bf(b.w);
  unsigned short* d = xpk + pk_idx(row, k0);
  *reinterpret_cast<us4*>(d)     = o0;
  *reinterpret_cast<us4*>(d + 4) = o1;
}

// ---------------- main GEMM (v12 structure, proven best) ----------------
// BM=256, BN=128, BK=32. 512 thr = 8 waves (4m x 2n): wave = 64 rows x 64 cols,
// acc = 4 x f32x16 (64 AGPR). B-only LDS ring-3 (48 KB) -> 2 WG/CU, DISJOINT B.
// A per-tile global->reg from packed image (L2-hot). One barrier/tile, counted
// WAITV(2). OUTMODE: 0 = bias+relu -> packed bf16, 1 = bf16 partials,
// 2 = rowmajor bf16.

#define WAITV(N) asm volatile("s_waitcnt vmcnt(" #N ")" ::: "memory")

#define STAGEB(BUF, T) do { \
    gload16(bsrc + (size_t)(T) * 32 * NHID,       &Blds[BUF][(w * 4 + 0) * 128]); \
    gload16(bsrc + ((size_t)(T) * 32 + 2) * NHID, &Blds[BUF][(w * 4 + 2) * 128]); \
  } while (0)

#define LOADA(T) do { \
    const unsigned short* ap_ = asrc + (size_t)(T) * 8192; \
    rA[0] = *reinterpret_cast<const short8*>(ap_); \
    rA[1] = *reinterpret_cast<const short8*>(ap_ + 4096); \
    rA[2] = *reinterpret_cast<const short8*>(ap_ + 256); \
    rA[3] = *reinterpret_cast<const short8*>(ap_ + 4096 + 256); \
  } while (0)

#define COMPUTE(BC) do { \
    const float* bb_ = &Blds[BC][0]; \
    _Pragma("unroll") \
    for (int ks_ = 0; ks_ < 2; ++ks_) { \
      short8 bfr_[2]; \
      _Pragma("unroll") \
      for (int nb_ = 0; nb_ < 2; ++nb_) { \
        float tf_[8]; \
        _Pragma("unroll") \
        for (int jj_ = 0; jj_ < 8; ++jj_) \
          tf_[jj_] = bb_[(ks_ * 16 + hi * 8 + jj_) * 128 + wn * 64 + nb_ * 32 + l31]; \
        _Pragma("unroll") \
        for (int jj_ = 0; jj_ < 8; ++jj_) bfr_[nb_][jj_] = f2bf_hw(tf_[jj_]); \
      } \
      acc[0] = __builtin_amdgcn_mfma_f32_32x32x16_bf16(rA[ks_],     bfr_[0], acc[0], 0, 0, 0); \
      acc[1] = __builtin_amdgcn_mfma_f32_32x32x16_bf16(rA[ks_],     bfr_[1], acc[1], 0, 0, 0); \
      acc[2] = __builtin_amdgcn_mfma_f32_32x32x16_bf16(rA[2 + ks_], bfr_[0], acc[2], 0, 0, 0); \
      acc[3] = __builtin_amdgcn_mfma_f32_32x32x16_bf16(rA[2 + ks_], bfr_[1], acc[3], 0, 0, 0); \
    } \
  } while (0)

template<int OUTMODE, bool SWZ>
__global__ __launch_bounds__(512, 4)
void gemm_k2(const unsigned short* __restrict__ Apk, int KC,
             const float* __restrict__ B, const float* __restrict__ bias,
             unsigned short* __restrict__ Cf, unsigned short* __restrict__ Cpb)
{
  __shared__ float Blds[3][32 * 128];   // 48 KB ring-3

  int nidx, ks0;
  if (SWZ) {
    int b = blockIdx.x;                  // 496 = 62 groups x 8 xcd-slots
    int xcd = b & 7;
    ks0  = xcd >> 1;                     // 2 XCDs per k-chunk (A slice 2MB -> L2)
    nidx = (b >> 3) * 2 + (xcd & 1);     // 0..123
  } else {
    nidx = blockIdx.x; ks0 = blockIdx.y;
  }
  const int n0   = nidx * 128;
  const int k0   = ks0 * KC;
  const int tid  = threadIdx.x;
  const int w    = tid >> 6;
  const int lane = tid & 63;
  const int l31  = lane & 31;
  const int hi   = lane >> 5;
  const int wm   = w >> 1;     // rows wm*64..+63
  const int wn   = w & 1;      // cols wn*64..+63

  f32x16 acc[4] = {};   // [rb*2+nb], lives in AGPR
  short8 rA[4];

  const float* bsrc = B + (size_t)(k0 + w * 4 + hi) * NHID + n0 + l31 * 4;
  const unsigned short* asrc = Apk + (size_t)(k0 >> 4) * 4096 +
                               (size_t)(wm * 64 + l31 + 256 * hi) * 8;

  const int NT = KC >> 5;

  STAGEB(0, 0);
  STAGEB(1, 1);

  int bc = 0;
  for (int t = 0; t < NT; ++t) {
    if (t + 1 < NT) { WAITV(2); } else { WAITV(0); }
    __builtin_amdgcn_sched_barrier(0);
    __builtin_amdgcn_s_barrier();            // all waves' stage(t) landed
    LOADA(t);                                 // issued BEFORE next stage
    if (t + 2 < NT) { int sb_ = bc >= 1 ? bc - 1 : 2; STAGEB(sb_, t + 2); }
    COMPUTE(bc);
    bc = bc == 2 ? 0 : bc + 1;
  }

  // epilogue: verified mapping col=base+l31, row=(reg&3)+8*(reg>>2)+4*hi
#pragma unroll
  for (int rb = 0; rb < 2; ++rb) {
#pragma unroll
    for (int nb = 0; nb < 2; ++nb) {
      int col = n0 + wn * 64 + nb * 32 + l31;
      float bv = (OUTMODE != 1) ? bias[col] : 0.f;
#pragma unroll
      for (int reg = 0; reg < 16; ++reg) {
        int row = wm * 64 + rb * 32 + (reg & 3) + 8 * (reg >> 2) + 4 * hi;
        float v = acc[rb * 2 + nb][reg];
        if (OUTMODE == 0) {
          v += bv; v = v > 0.f ? v : 0.f;
          Cf[pk_idx(row, col)] = f2bf(v);
        } else if (OUTMODE == 1) {
          Cpb[(size_t)ks0 * PLANE + (size_t)row * NHID + col] = f2bf(v);
        } else {
          v += bv; v = v > 0.f ? v : 0.f;
          Cf[(size_t)row * NHID + col] = f2bf(v);
        }
      }
    }
  }
}

// ---------------- reduce bf16 partials -> packed bf16 (GEMM1 path) ----------------
__global__ void reduce_hb_pack(const unsigned short* __restrict__ part,
                               const float* __restrict__ bias,
                               unsigned short* __restrict__ out, int S) {
  int g8 = blockIdx.x * 256 + threadIdx.x;     // < 256*1984 (chunks of 8)
  int row = g8 / 1984;
  int c   = (g8 - row * 1984) * 8;
  size_t off = (size_t)row * NHID + c;
  float s[8] = {0.f, 0.f, 0.f, 0.f, 0.f, 0.f, 0.f, 0.f};
  for (int k = 0; k < S; ++k) {
    short8 p = *reinterpret_cast<const short8*>(part + (size_t)k * PLANE + off);
#pragma unroll
    for (int j = 0; j < 8; ++j) s[j] += bf2f((unsigned short)p[j]);
  }
  short8 o;
#pragma unroll
  for (int j = 0; j < 8; ++j) {
    float v = s[j] + bias[c + j];
    v = v > 0.f ? v : 0.f;
    o[j] = (short)f2bf(v);
  }
  *reinterpret_cast<short8*>(out + pk_idx(row, c)) = o;   // c%8==0 -> contiguous
}

// ---------------- fold Wout [15872][992] -> Wv [15872][32] ----------------
__global__ void wv_fold(const float* __restrict__ Wout, float* __restrict__ Wv) {
  int g = blockIdx.x * 256 + threadIdx.x;
  int k = g >> 5, c = g & 31;
  const float* row = Wout + (size_t)k * 992;
  float s = 0.f;
#pragma unroll
  for (int o = 0; o < 32; ++o) {
    if (o == c) continue;
    int i = c < o ? c : o;
    int j = c < o ? o : c;
    int p = 31 * i - (i * (i - 1)) / 2 + (j - i - 1);
    s += row[2 * p + (c > o ? 1 : 0)];
  }
  Wv[g] = s;
}

// ---------------- FUSED votes partial: relu(sum4 + b2) dot Wv, K-split 32 ----------------
__global__ void votes_partial_f(const unsigned short* __restrict__ pb,
                                const float* __restrict__ b2,
                                const float* __restrict__ Wv,
                                float* __restrict__ part) {
  int bm = blockIdx.x >> 5;
  int ks = blockIdx.x & 31;
  int r  = bm * 8 + (threadIdx.x >> 5);
  int c  = threadIdx.x & 31;
  size_t rowoff = (size_t)r * NHID + ks * 496;
  const float* wp = Wv + (size_t)(ks * 496) * 32 + c;
  const float* bp = b2 + ks * 496;
  float s = 0.f;
  for (int k0 = 0; k0 < 496; k0 += 8) {
    short8 p0 = *reinterpret_cast<const short8*>(pb + 0 * PLANE + rowoff + k0);
    short8 p1 = *reinterpret_cast<const short8*>(pb + 1 * PLANE + rowoff + k0);
    short8 p2 = *reinterpret_cast<const short8*>(pb + 2 * PLANE + rowoff + k0);
    short8 p3 = *reinterpret_cast<const short8*>(pb + 3 * PLANE + rowoff + k0);
#pragma unroll
    for (int j = 0; j < 8; ++j) {
      float h = bf2f((unsigned short)p0[j]) + bf2f((unsigned short)p1[j]) +
                bf2f((unsigned short)p2[j]) + bf2f((unsigned short)p3[j]) +
                bp[k0 + j];
      h = h > 0.f ? h : 0.f;
      s += h * wp[(size_t)(k0 + j) * 32];
    }
  }
  part[(size_t)(ks * 256 + r) * 32 + c] = s;
}

// ---------------- unfused votes partial (fallback path) ----------------
__global__ void votes_partial(const unsigned short* __restrict__ h2,
                              const float* __restrict__ Wv,
                              float* __restrict__ part) {
  int bm = blockIdx.x >> 5;
  int ks = blockIdx.x & 31;
  int r  = bm * 8 + (threadIdx.x >> 5);
  int c  = threadIdx.x & 31;
  const unsigned short* hrow = h2 + (size_t)r * NHID + ks * 496;
  const float* wp = Wv + (size_t)(ks * 496) * 32 + c;
  float s = 0.f;
  for (int k0 = 0; k0 < 496; k0 += 8) {
    short8 hv = *reinterpret_cast<const short8*>(hrow + k0);
#pragma unroll
    for (int j = 0; j < 8; ++j)
      s += bf2f((unsigned short)hv[j]) * wp[(size_t)(k0 + j) * 32];
  }
  part[(size_t)(ks * 256 + r) * 32 + c] = s;
}

// ---------------- reduce votes + bias-fold ----------------
__global__ void votes_reduce(const float* __restrict__ part,
                             const float* __restrict__ bout,
                             float* __restrict__ out) {
  int g = blockIdx.x * 256 + threadIdx.x;
  int c = g & 31;
  float s = 0.f;
#pragma unroll
  for (int ks = 0; ks < 32; ++ks) s += part[(size_t)ks * 8192 + g];
  float bv = 0.f;
#pragma unroll
  for (int o = 0; o < 32; ++o) {
    if (o == c) continue;
    int i = c < o ? c : o;
    int j = c < o ? o : c;
    int p = 31 * i - (i * (i - 1)) / 2 + (j - i - 1);
    bv += bout[2 * p + (c > o ? 1 : 0)];
  }
  out[g] = s + bv;
}

extern "C" void kernel_launch(void* const* d_in, const int* in_sizes, int n_in,
                              void* d_out, int out_size, void* d_ws, size_t ws_size,
                              hipStream_t stream) {
  const float* x    = (const float*)d_in[0];
  const float* W1   = (const float*)d_in[1];
  const float* b1   = (const float*)d_in[2];
  const float* W2   = (const float*)d_in[3];
  const float* b2   = (const float*)d_in[4];
  const float* Wout = (const float*)d_in[5];
  const float* bout = (const float*)d_in[6];
  float* out = (float*)d_out;

  char* ws = (char*)d_ws;
  unsigned short* xpk  = (unsigned short*)(ws);                     // 262144
  unsigned short* h1pk = (unsigned short*)(ws + 262144);            // 8126464
  unsigned short* h2   = (unsigned short*)(ws + 8388608);           // 8126464 (fallback only)
  float*          Wv   = (float*)(ws + 16515072);                   // 2031616
  float*          part = (float*)(ws + 18546688);                   // 1048576
  unsigned short* pb   = (unsigned short*)(ws + 19595264);          // 4 planes = 32.5 MB

  const size_t PARTB = PLANE * 2;   // 8,126,464 bytes per bf16 partial plane
  const bool split = ws_size >= 19595264ull + 4 * PARTB;

  hipLaunchKernelGGL(cvt_x_pack, dim3(64), dim3(256), 0, stream, x, xpk);
  if (split) {
    // GEMM1: K=512 split 2 ways -> bf16 partials -> packed h1
    hipLaunchKernelGGL((gemm_k2<1, false>), dim3(124, 2), dim3(512), 0, stream,
                       xpk, 256, W1, (const float*)nullptr,
                       (unsigned short*)nullptr, pb);
    hipLaunchKernelGGL(reduce_hb_pack, dim3(1984), dim3(256), 0, stream,
                       pb, b1, h1pk, 2);
    // GEMM2: K=15872 split 4 ways, 496 WGs (all-resident), bf16 partials
    hipLaunchKernelGGL((gemm_k2<1, true>), dim3(496), dim3(512), 0, stream,
                       h1pk, 3968, W2, (const float*)nullptr,
                       (unsigned short*)nullptr, pb);
    hipLaunchKernelGGL(wv_fold, dim3(1984), dim3(256), 0, stream, Wout, Wv);
    // fused: relu(sum partials + b2) folded into the vote GEMV
    hipLaunchKernelGGL(votes_partial_f, dim3(1024), dim3(256), 0, stream,
                       pb, b2, Wv, part);
  } else {
    hipLaunchKernelGGL((gemm_k2<0, false>), dim3(124, 1), dim3(512), 0, stream,
                       xpk, 512, W1, b1, h1pk, (unsigned short*)nullptr);
    hipLaunchKernelGGL((gemm_k2<2, false>), dim3(124, 1), dim3(512), 0, stream,
                       h1pk, NHID, W2, b2, h2, (unsigned short*)nullptr);
    hipLaunchKernelGGL(wv_fold, dim3(1984), dim3(256), 0, stream, Wout, Wv);
    hipLaunchKernelGGL(votes_partial, dim3(1024), dim3(256), 0, stream, h2, Wv, part);
  }
  hipLaunchKernelGGL(votes_reduce, dim3(32), dim3(256), 0, stream, part, bout, out);
}